// Round 2
// baseline (3425.495 us; speedup 1.0000x reference)
//
#include <hip/hip_runtime.h>
#include <math.h>

#define NGROUP 4
#define BATCH  4096
#define TSTEPS 128

// ---------------- workspace layout (float offsets) ----------------
#define WI0T_OFF 0               // 4*48*64*4  = 49152  : Wi0t[g][k][u][s]
#define WH0T_OFF 49152           // 4*64*64*4  = 65536  : Wh0t[g][k][u][s]
#define B0T_OFF  114688          // 4*64*4     = 1024   : b0t[g][u][s]
#define KAL_OFF  115712          // 4*128*48   = 24576  : per (g,t): K[24], Sinv[16], logdet[1]
#define LL_OFF   147456          // 4*128*4096 = 2097152
#define XN_OFF   (147456 + 2097152)   // 4*128*4096*6 = 12582912

// ---------------- shared-memory layout (float offsets) ----------------
#define SM_WI0   0               // 12288 : Wi0t[g] as [k][u][4]
#define SM_WH0   12288           // 16384 : Wh0t[g] as [k][u][4]
#define SM_WE1   28672           // 912
#define SM_BE1   29584           // 48
#define SM_WE2   29632           // 2304
#define SM_BE2   31936           // 48
#define SM_WI1   31984           // 1024 packed float2 {q, q+8}
#define SM_WH1   33008           // 64   packed float2
#define SM_B1L   33072           // 16
#define SM_B0T   33088           // 256
#define SM_WAVE  33344
#define PER_WAVE 544             // h0b 512 | h1b 32
#define SMEM_FLOATS (33344 + 8*544)   // 37696 floats = 150784 bytes

__device__ __forceinline__ float fast_sig(float x) {
    return __builtin_amdgcn_rcpf(1.0f + __expf(-x));
}
__device__ __forceinline__ float fast_tanh(float x) {
    float ax = fabsf(x);
    float t  = __expf(-2.0f * ax);
    float r  = (1.0f - t) * __builtin_amdgcn_rcpf(1.0f + t);
    return copysignf(r, x);
}
__device__ __forceinline__ float rl(float v, int lane) {
    return __int_as_float(__builtin_amdgcn_readlane(__float_as_int(v), lane));
}

// ============ prep 1: transpose LSTM0 weights into [k][u][gate4] ============
__global__ void nkf_prep_tr(const float* __restrict__ Wi0, const float* __restrict__ Wh0,
                            const float* __restrict__ b0, float* __restrict__ ws) {
    int idx = blockIdx.x * 256 + threadIdx.x;
    if (idx < 49152) {
        int g = idx / 12288, r2 = idx % 12288;
        int k = r2 >> 8, u = (r2 & 255) >> 2, s = r2 & 3;
        ws[WI0T_OFF + idx] = Wi0[g * 12288 + k * 256 + s * 64 + u];
    } else if (idx < 49152 + 65536) {
        int j = idx - 49152;
        int g = j / 16384, r2 = j % 16384;
        int k = r2 >> 8, u = (r2 & 255) >> 2, s = r2 & 3;
        ws[WH0T_OFF + j] = Wh0[g * 16384 + k * 256 + s * 64 + u];
    } else if (idx < 49152 + 65536 + 1024) {
        int j = idx - 114688;
        int g = j >> 8, r2 = j & 255;
        int u = r2 >> 2, s = r2 & 3;
        ws[B0T_OFF + j] = b0[g * 256 + s * 64 + u];
    }
}

// ============ prep 2: data-independent Kalman gain sequence ============
__global__ void nkf_prep_kal(const float* __restrict__ Q_log, const float* __restrict__ R_log,
                             float* __restrict__ ws) {
    int g = blockIdx.x * blockDim.x + threadIdx.x;
    if (g >= NGROUP) return;
    float Qd[6], Rd[4];
#pragma unroll
    for (int i = 0; i < 6; i++) Qd[i] = expf(Q_log[g * 6 + i]);
#pragma unroll
    for (int i = 0; i < 4; i++) Rd[i] = expf(R_log[i]);
    float P[6][6];
#pragma unroll
    for (int i = 0; i < 6; i++)
#pragma unroll
        for (int j = 0; j < 6; j++) P[i][j] = (i == j) ? 1000.0f : 0.0f;
    float* ko = ws + KAL_OFF + (size_t)g * (TSTEPS * 48);

#pragma unroll 1
    for (int t = 0; t < TSTEPS; t++) {
        float FP[6][6], Pp[6][6];
#pragma unroll
        for (int i = 0; i < 6; i++)
#pragma unroll
            for (int j = 0; j < 6; j++) FP[i][j] = P[i][j] + ((i < 3) ? P[i + 3][j] : 0.0f);
#pragma unroll
        for (int i = 0; i < 6; i++)
#pragma unroll
            for (int j = 0; j < 6; j++) Pp[i][j] = FP[i][j] + ((j < 3) ? FP[i][j + 3] : 0.0f);
#pragma unroll
        for (int i = 0; i < 6; i++) Pp[i][i] += Qd[i];

        float S[4][4];
#pragma unroll
        for (int i = 0; i < 4; i++)
#pragma unroll
            for (int j = 0; j < 4; j++) S[i][j] = Pp[i][j] + ((i == j) ? Rd[i] : 0.0f);

        float L[4][4];
#pragma unroll
        for (int j = 0; j < 4; j++) {
            float d = S[j][j];
            for (int k = 0; k < j; k++) d -= L[j][k] * L[j][k];
            L[j][j] = sqrtf(d);
            float inv = 1.0f / L[j][j];
            for (int i = j + 1; i < 4; i++) {
                float s2 = S[i][j];
                for (int k = 0; k < j; k++) s2 -= L[i][k] * L[j][k];
                L[i][j] = s2 * inv;
            }
        }
        float logdet = 2.0f * (logf(L[0][0]) + logf(L[1][1]) + logf(L[2][2]) + logf(L[3][3]));

        float Li[4][4];
#pragma unroll
        for (int j = 0; j < 4; j++) {
            Li[j][j] = 1.0f / L[j][j];
            for (int i = j + 1; i < 4; i++) {
                float s2 = 0.0f;
                for (int k = j; k < i; k++) s2 += L[i][k] * Li[k][j];
                Li[i][j] = -s2 / L[i][i];
            }
        }
        float Si[4][4];
#pragma unroll
        for (int i = 0; i < 4; i++)
#pragma unroll
            for (int j = 0; j < 4; j++) {
                float s2 = 0.0f;
                for (int k = (i > j ? i : j); k < 4; k++) s2 += Li[k][i] * Li[k][j];
                Si[i][j] = s2;
            }
        float K[6][4];
#pragma unroll
        for (int i = 0; i < 6; i++)
#pragma unroll
            for (int o = 0; o < 4; o++) {
                float s2 = 0.0f;
                for (int m = 0; m < 4; m++) s2 += Pp[i][m] * Si[m][o];
                K[i][o] = s2;
            }
#pragma unroll
        for (int i = 0; i < 6; i++)
#pragma unroll
            for (int o = 0; o < 4; o++) ko[t * 48 + i * 4 + o] = K[i][o];
#pragma unroll
        for (int i = 0; i < 4; i++)
#pragma unroll
            for (int j = 0; j < 4; j++) ko[t * 48 + 24 + i * 4 + j] = Si[i][j];
        ko[t * 48 + 40] = logdet;

        float Pn[6][6];
#pragma unroll
        for (int i = 0; i < 6; i++)
#pragma unroll
            for (int j = 0; j < 6; j++) {
                float s2 = Pp[i][j];
                for (int m = 0; m < 4; m++) s2 -= K[i][m] * Pp[m][j];
                Pn[i][j] = s2;
            }
#pragma unroll
        for (int i = 0; i < 6; i++)
#pragma unroll
            for (int j = 0; j < 6; j++) P[i][j] = Pn[i][j];
    }
}

// Kalman constants held in lanes 48..63: ktA=kt[j], ktB=kt[16+j], ktC=kt[32+j]
#define KT(i) ((i) < 16 ? rl(ktA, 48 + (i)) : ((i) < 32 ? rl(ktB, 32 + (i)) : rl(ktC, 16 + (i))))

// ============ main: 256 blocks x 512 threads; wave = 8 chains of one group ============
__global__ __launch_bounds__(512, 2) void nkf_main(
    const float* __restrict__ z, const float* __restrict__ x0,
    const float* __restrict__ We1, const float* __restrict__ be1,
    const float* __restrict__ We2, const float* __restrict__ be2,
    const float* __restrict__ Wi1, const float* __restrict__ Wh1,
    const float* __restrict__ b1l, const float* __restrict__ ws,
    float* __restrict__ ll_out, float* __restrict__ xn_out) {
    extern __shared__ float sm[];
    const int tid  = threadIdx.x;
    const int g    = blockIdx.x >> 6;
    const int bblk = blockIdx.x & 63;
    const int w    = tid >> 6;
    const int l    = tid & 63;

    {   // cooperative weight staging
        const float* wi0g = ws + WI0T_OFF + g * 12288;
        for (int i = tid; i < 12288; i += 512) sm[SM_WI0 + i] = wi0g[i];
        const float* wh0g = ws + WH0T_OFF + g * 16384;
        for (int i = tid; i < 16384; i += 512) sm[SM_WH0 + i] = wh0g[i];
        for (int i = tid; i < 912; i += 512) sm[SM_WE1 + i] = We1[i];
        if (tid < 48) sm[SM_BE1 + tid] = be1[tid];
        for (int i = tid; i < 2304; i += 512) sm[SM_WE2 + i] = We2[i];
        if (tid < 48) sm[SM_BE2 + tid] = be2[tid];
        for (int i = tid; i < 1024; i += 512) {      // pack Wi1 as [k][r]{q,q+8}
            int k = i >> 4, q = i & 15;
            sm[SM_WI1 + k * 16 + (q & 7) * 2 + (q >> 3)] = Wi1[g * 1024 + i];
        }
        if (tid < 64) {
            int j = tid >> 4, q = tid & 15;
            sm[SM_WH1 + j * 16 + (q & 7) * 2 + (q >> 3)] = Wh1[g * 64 + tid];
        }
        if (tid < 16) sm[SM_B1L + tid] = b1l[g * 16 + tid];
        const float* b0tp = ws + B0T_OFF + g * 256;
        if (tid < 256) sm[SM_B0T + tid] = b0tp[tid];
    }
    __syncthreads();

    float* h0b = sm + SM_WAVE + w * PER_WAVE;
    float* h1b = h0b + 512;

    const int c  = l >> 3, r = l & 7;
    const int bq = bblk * 64 + w * 8 + c;   // batch index for chain-phases

    float c0v[8], hn[8];
#pragma unroll
    for (int i = 0; i < 8; i++) { c0v[i] = 0.0f; hn[i] = 0.0f; }
    if (l < 32) h1b[l] = 0.0f;
    float c1u = 0.0f;
    float xr[6] = {0, 0, 0, 0, 0, 0};
    float zcur[4] = {0, 0, 0, 0};
    if (r == 0) {
#pragma unroll
        for (int i = 0; i < 6; i++) xr[i] = x0[bq * 6 + i];
        const float* zp = z + (size_t)bq * (TSTEPS * 4);
        zcur[0] = zp[0]; zcur[1] = zp[1]; zcur[2] = zp[2]; zcur[3] = zp[3];
    }
    const float* kal = ws + KAL_OFF + (size_t)g * (TSTEPS * 48);

    for (int t = 0; t < TSTEPS; ++t) {
        // ---- prefetch Kalman constants for this t into lanes 48..63 ----
        float ktA = 0.0f, ktB = 0.0f, ktC = 0.0f;
        if (l >= 48) {
            const float* kt = kal + t * 48 + (l - 48);
            ktA = kt[0]; ktB = kt[16]; ktC = kt[32];
        }
        // ---- prefetch next z (r==0 lanes) ----
        float znx0 = 0, znx1 = 0, znx2 = 0, znx3 = 0;
        if (r == 0) {
            int tn = (t + 1 < TSTEPS) ? t + 1 : t;
            const float* zp = z + ((size_t)bq * TSTEPS + tn) * 4;
            znx0 = zp[0]; znx1 = zp[1]; znx2 = zp[2]; znx3 = zp[3];
        }
        // ---------- feats in registers (r==0 lanes) ----------
        float f[19];
        if (r == 0) {
            f[0] = zcur[0]; f[1] = zcur[1]; f[2] = zcur[2]; f[3] = zcur[3];
#pragma unroll
            for (int i = 0; i < 6; i++) f[4 + i] = xr[i];
            float i0 = zcur[0] - xr[0], i1 = zcur[1] - xr[1];
            float i2 = zcur[2] - xr[2], i3 = zcur[3] - xr[3];
            f[10] = i0; f[11] = i1; f[12] = i2; f[13] = i3;
            f[14] = sqrtf(i0 * i0 + i1 * i1 + i2 * i2 + i3 * i3);
            f[15] = sqrtf(xr[0] * xr[0] + xr[1] * xr[1] + xr[2] * xr[2]);
            f[16] = sqrtf(xr[3] * xr[3] + xr[4] * xr[4] + xr[5] * xr[5]);
            f[17] = (float)t * 0.01f;
            f[18] = 1.0f;
        }
        // ---------- E1: lanes 0..47, feats via readlane ----------
        float e1[8];
        if (l < 48) {
            float bb = sm[SM_BE1 + l];
#pragma unroll
            for (int i = 0; i < 8; i++) e1[i] = bb;
#pragma unroll
            for (int k = 0; k < 19; k++) {
                float wv = sm[SM_WE1 + k * 48 + l];
#pragma unroll
                for (int i = 0; i < 8; i++) e1[i] += wv * rl(f[k], i * 8);
            }
#pragma unroll
            for (int i = 0; i < 8; i++) e1[i] = fmaxf(e1[i], 0.0f);
        }
        // ---------- E2: lanes 0..47, e1 via readlane ----------
        float e2[8];
        if (l < 48) {
            float bb = sm[SM_BE2 + l];
#pragma unroll
            for (int i = 0; i < 8; i++) e2[i] = bb;
#pragma unroll 4
            for (int k = 0; k < 48; k++) {
                float wv = sm[SM_WE2 + k * 48 + l];
#pragma unroll
                for (int i = 0; i < 8; i++) e2[i] += wv * rl(e1[i], k);
            }
#pragma unroll
            for (int i = 0; i < 8; i++) e2[i] = fmaxf(e2[i], 0.0f);
        }
        // ---------- LSTM0 gates: lane = unit, activations via readlane ----------
        float ac0[8], ac1[8], ac2[8], ac3[8];
        {
            float4 bb = *(const float4*)&sm[SM_B0T + l * 4];
#pragma unroll
            for (int i = 0; i < 8; i++) { ac0[i] = bb.x; ac1[i] = bb.y; ac2[i] = bb.z; ac3[i] = bb.w; }
        }
#pragma unroll 4
        for (int k = 0; k < 48; k++) {
            float4 wv = *(const float4*)&sm[SM_WI0 + (k * 64 + l) * 4];
#pragma unroll
            for (int i = 0; i < 8; i++) {
                float ev = rl(e2[i], k);
                ac0[i] += wv.x * ev; ac1[i] += wv.y * ev;
                ac2[i] += wv.z * ev; ac3[i] += wv.w * ev;
            }
        }
#pragma unroll 4
        for (int k = 0; k < 64; k++) {
            float4 wv = *(const float4*)&sm[SM_WH0 + (k * 64 + l) * 4];
#pragma unroll
            for (int i = 0; i < 8; i++) {
                float hv = rl(hn[i], k);
                ac0[i] += wv.x * hv; ac1[i] += wv.y * hv;
                ac2[i] += wv.z * hv; ac3[i] += wv.w * hv;
            }
        }
        float hnew[8];
#pragma unroll
        for (int i = 0; i < 8; i++) {
            float cn = fast_sig(ac1[i]) * c0v[i] + fast_sig(ac0[i]) * fast_tanh(ac2[i]);
            c0v[i] = cn;
            hnew[i] = fast_sig(ac3[i]) * fast_tanh(cn);
        }
#pragma unroll
        for (int i = 0; i < 8; i++) hn[i] = hnew[i];
        // stage h0 to LDS for LSTM1 (plain layout; writes are cheap)
        {
            float4 o0 = {hn[0], hn[1], hn[2], hn[3]};
            float4 o1 = {hn[4], hn[5], hn[6], hn[7]};
            *(float4*)&h0b[l * 8]     = o0;
            *(float4*)&h0b[l * 8 + 4] = o1;
        }
        asm volatile("" ::: "memory");
        // ---------- LSTM1: chain c = l>>3, gates q0=r, q1=r+8 ----------
        float ga  = sm[SM_B1L + r];
        float gb2 = sm[SM_B1L + r + 8];
#pragma unroll 4
        for (int k = 0; k < 64; k++) {
            float  hv = h0b[k * 8 + c];
            float2 wp = *(const float2*)&sm[SM_WI1 + k * 16 + r * 2];
            ga  += wp.x * hv;
            gb2 += wp.y * hv;
        }
#pragma unroll
        for (int j = 0; j < 4; j++) {
            float  hv = h1b[j * 8 + c];
            float2 wp = *(const float2*)&sm[SM_WH1 + j * 16 + r * 2];
            ga  += wp.x * hv;
            gb2 += wp.y * hv;
        }
        float fO = __shfl_xor(ga, 4, 64);
        float oO = __shfl_xor(gb2, 4, 64);
        asm volatile("" ::: "memory");
        if (r < 4) {
            float cn = fast_sig(fO) * c1u + fast_sig(ga) * fast_tanh(gb2);
            c1u = cn;
            h1b[r * 8 + c] = fast_sig(oO) * fast_tanh(cn);
        }
        asm volatile("" ::: "memory");
        // ---------- Kalman measurement update (lane r==0) ----------
        if (r == 0) {
            float logp = h1b[c];
            float a0 = h1b[8 + c], a1 = h1b[16 + c], a2 = h1b[24 + c];
            float xp0 = xr[0] + xr[3] + 0.5f * a0;   // DT = 1
            float xp1 = xr[1] + xr[4] + 0.5f * a1;
            float xp2 = xr[2] + xr[5] + 0.5f * a2;
            float xp3 = xr[3] + a0;
            float xp4 = xr[4] + a1;
            float xp5 = xr[5] + a2;
            float y0 = zcur[0] - xp0, y1 = zcur[1] - xp1;
            float y2 = zcur[2] - xp2, y3 = zcur[3] - xp3;
            float xn0 = xp0 + KT(0)  * y0 + KT(1)  * y1 + KT(2)  * y2 + KT(3)  * y3;
            float xn1 = xp1 + KT(4)  * y0 + KT(5)  * y1 + KT(6)  * y2 + KT(7)  * y3;
            float xn2 = xp2 + KT(8)  * y0 + KT(9)  * y1 + KT(10) * y2 + KT(11) * y3;
            float xn3 = xp3 + KT(12) * y0 + KT(13) * y1 + KT(14) * y2 + KT(15) * y3;
            float xn4 = xp4 + KT(16) * y0 + KT(17) * y1 + KT(18) * y2 + KT(19) * y3;
            float xn5 = xp5 + KT(20) * y0 + KT(21) * y1 + KT(22) * y2 + KT(23) * y3;
            float sy0 = KT(24) * y0 + KT(25) * y1 + KT(26) * y2 + KT(27) * y3;
            float sy1 = KT(28) * y0 + KT(29) * y1 + KT(30) * y2 + KT(31) * y3;
            float sy2 = KT(32) * y0 + KT(33) * y1 + KT(34) * y2 + KT(35) * y3;
            float sy3 = KT(36) * y0 + KT(37) * y1 + KT(38) * y2 + KT(39) * y3;
            float quad = y0 * sy0 + y1 * sy1 + y2 * sy2 + y3 * sy3;
            float llv  = logp - 0.5f * (quad + KT(40));
            size_t base = ((size_t)(g * TSTEPS + t)) * BATCH + bq;
            ll_out[base] = llv;
            float* xo = xn_out + base * 6;
            xo[0] = xn0; xo[1] = xn1; xo[2] = xn2;
            xo[3] = xn3; xo[4] = xn4; xo[5] = xn5;
            xr[0] = xn0; xr[1] = xn1; xr[2] = xn2;
            xr[3] = xn3; xr[4] = xn4; xr[5] = xn5;
        }
        zcur[0] = znx0; zcur[1] = znx1; zcur[2] = znx2; zcur[3] = znx3;
    }
}

// ============ argmax over groups + gather output ============
__global__ void nkf_gather(const float* __restrict__ ws, float* __restrict__ out) {
    int idx = blockIdx.x * 256 + threadIdx.x;   // t*BATCH + b
    if (idx >= TSTEPS * BATCH) return;
    const float* llp = ws + LL_OFF;
    float best = llp[idx];
    int   bg   = 0;
#pragma unroll
    for (int g2 = 1; g2 < 4; g2++) {
        float v = llp[(size_t)g2 * (TSTEPS * BATCH) + idx];
        if (v > best) { best = v; bg = g2; }
    }
    const float* xp = ws + XN_OFF + ((size_t)bg * (TSTEPS * BATCH) + idx) * 6;
    float* o = out + (size_t)idx * 6;
#pragma unroll
    for (int i = 0; i < 6; i++) o[i] = xp[i];
}

extern "C" void kernel_launch(void* const* d_in, const int* in_sizes, int n_in,
                              void* d_out, int out_size, void* d_ws, size_t ws_size,
                              hipStream_t stream) {
    const float* z   = (const float*)d_in[0];
    const float* x0  = (const float*)d_in[1];
    const float* We1 = (const float*)d_in[2];
    const float* be1 = (const float*)d_in[3];
    const float* We2 = (const float*)d_in[4];
    const float* be2 = (const float*)d_in[5];
    const float* Wi0 = (const float*)d_in[6];
    const float* Wh0 = (const float*)d_in[7];
    const float* b0  = (const float*)d_in[8];
    const float* Wi1 = (const float*)d_in[9];
    const float* Wh1 = (const float*)d_in[10];
    const float* b1l = (const float*)d_in[11];
    const float* Ql  = (const float*)d_in[12];
    const float* Rl  = (const float*)d_in[13];
    float* ws  = (float*)d_ws;
    float* out = (float*)d_out;

    hipFuncSetAttribute((const void*)nkf_main,
                        hipFuncAttributeMaxDynamicSharedMemorySize, SMEM_FLOATS * 4);

    nkf_prep_tr<<<(115712 + 255) / 256, 256, 0, stream>>>(Wi0, Wh0, b0, ws);
    nkf_prep_kal<<<1, 64, 0, stream>>>(Ql, Rl, ws);
    nkf_main<<<256, 512, SMEM_FLOATS * 4, stream>>>(z, x0, We1, be1, We2, be2,
                                                    Wi1, Wh1, b1l, ws,
                                                    ws + LL_OFF, ws + XN_OFF);
    nkf_gather<<<2048, 256, 0, stream>>>(ws, out);
}